// Round 6
// baseline (82.063 us; speedup 1.0000x reference)
//
#include <hip/hip_runtime.h>
#include <hip/hip_bf16.h>
#include <stdint.h>

typedef __bf16 bf16x8 __attribute__((ext_vector_type(8)));
typedef float f32x4 __attribute__((ext_vector_type(4)));

#define KDIM 256
#define MB 4608          // padded rows per batch (18 * 256)
#define MTOT 18432       // 4 * MB
#define QKVS 768         // fused q/k/v row stride

__device__ __forceinline__ float b2f(ushort u){
    union { float f; uint32_t i; } x; x.i = ((uint32_t)u) << 16; return x.f;
}
__device__ __forceinline__ ushort f2b(float f){
    uint32_t u = __float_as_uint(f);
    uint32_t r = (u + 0x7fffu + ((u >> 16) & 1u)) >> 16;
    return (ushort)r;
}

// --------- Kernel P1: single x pass -> bf16 CL transpose + fp32 LN partials -
__global__ __launch_bounds__(256)
void ln_fuse(const float* __restrict__ x, ushort* __restrict__ xt,
             float* __restrict__ psum, float* __restrict__ psum2){
    __shared__ ushort sh[128 * 68];
    __shared__ float ssum[16 * 132], ssum2[16 * 132];
    const int bid = blockIdx.x;
    const int b = bid >> 7, rem = bid & 127, h = rem >> 1, ch = (rem & 1) * 128;
    const int tid = threadIdx.x;
    const int csub = tid >> 4, w4 = tid & 15;
#pragma unroll
    for (int i = 0; i < 8; ++i){
        int c = csub + 16 * i;            // local channel 0..127
        float4 v = *(const float4*)(x + ((size_t)(b * 256 + ch + c)) * 4096
                                      + h * 64 + w4 * 4);
        ushort4 u; u.x = f2b(v.x); u.y = f2b(v.y); u.z = f2b(v.z); u.w = f2b(v.w);
        *(ushort4*)&sh[c * 68 + w4 * 4] = u;
        ssum [w4 * 132 + c] = v.x + v.y + v.z + v.w;
        ssum2[w4 * 132 + c] = v.x * v.x + v.y * v.y + v.z * v.z + v.w * v.w;
    }
    __syncthreads();
    if (tid < 128){
        float S = 0.f, S2 = 0.f;
#pragma unroll
        for (int j = 0; j < 16; ++j){ S += ssum[j * 132 + tid]; S2 += ssum2[j * 132 + tid]; }
        psum [(b * 64 + h) * 256 + ch + tid] = S;
        psum2[(b * 64 + h) * 256 + ch + tid] = S2;
    }
    const int c16 = tid & 15, w16 = tid >> 4;
#pragma unroll
    for (int p = 0; p < 4; ++p){
        int w = p * 16 + w16;
        union { ushort u[8]; uint4 v; } r;
#pragma unroll
        for (int j = 0; j < 8; ++j) r.u[j] = sh[(c16 * 8 + j) * 68 + w];
        size_t row = (size_t)b * MB + (size_t)(h + 1) * 66 + (w + 1);
        *(uint4*)(xt + row * 256 + ch + c16 * 8) = r.v;
    }
}

// --------- P2: per-b scaled weights + folded bias + pad fill (block-range) --
// [0,192):   qkv weight transpose, 4 b-copies scaled by rv[b,k] (q also /16)
// [192,256): Wo transpose (unscaled)
// [256,268): folded bias: biasp[b][n] = qs*(bias[n] - sum_c m*rv*W[c,n])
// [268,332): fill 512 pad/tail rows per b with bf16(mean[b,c])
__global__ __launch_bounds__(256)
void prep2(const float* __restrict__ Wq, const float* __restrict__ bq,
           const float* __restrict__ Wk, const float* __restrict__ bk,
           const float* __restrict__ Wv, const float* __restrict__ bv,
           const float* __restrict__ Wo,
           const float* __restrict__ psum, const float* __restrict__ psum2,
           ushort* __restrict__ wtq, ushort* __restrict__ wot,
           float* __restrict__ biasp, ushort* __restrict__ xt){
    __shared__ float shW[32 * 33];
    __shared__ float shS[8 * 32], shS2[8 * 32], shRV[4 * 32], shM[256];
    const int bid = blockIdx.x, tid = threadIdx.x;
    if (bid < 192){
        int mat = bid / 64, tile = bid % 64;
        int ti = tile & 7, tj = tile >> 3;
        {
            int kk = tid & 31, idx = tid >> 5;        // idx: b*2 + h-half
            int b = idx >> 1, h0 = (idx & 1) * 32;
            float S = 0.f, S2 = 0.f;
            for (int r = 0; r < 32; ++r){
                int off = (b * 64 + h0 + r) * 256 + tj * 32 + kk;
                S += psum[off]; S2 += psum2[off];
            }
            shS[idx * 32 + kk] = S; shS2[idx * 32 + kk] = S2;
        }
        __syncthreads();
        if (tid < 128){
            int b = tid >> 5, kk = tid & 31;
            float S  = shS [(b * 2) * 32 + kk] + shS [(b * 2 + 1) * 32 + kk];
            float S2 = shS2[(b * 2) * 32 + kk] + shS2[(b * 2 + 1) * 32 + kk];
            float m = S * (1.f / 4096.f);
            float v = S2 * (1.f / 4096.f) - m * m;
            shRV[b * 32 + kk] = rsqrtf(v + 1e-5f);
        }
        const float* src = (mat == 0) ? Wq : (mat == 1) ? Wk : Wv;
        float qs = (mat == 0) ? 0.0625f : 1.0f;
        int tx = tid & 31, ty = tid >> 5;
#pragma unroll
        for (int i = 0; i < 4; ++i)
            shW[(ty + i * 8) * 33 + tx] =
                src[(size_t)(tj * 32 + ty + i * 8) * 256 + ti * 32 + tx] * qs;
        __syncthreads();
#pragma unroll
        for (int b = 0; b < 4; ++b){
            float rv = shRV[b * 32 + tx];
#pragma unroll
            for (int i = 0; i < 4; ++i){
                int n = mat * 256 + ti * 32 + ty + i * 8;
                wtq[((size_t)b * 768 + n) * 256 + tj * 32 + tx] =
                    f2b(shW[tx * 33 + ty + i * 8] * rv);
            }
        }
    } else if (bid < 256){
        int tile = bid - 192;
        int ti = tile & 7, tj = tile >> 3;
        int tx = tid & 31, ty = tid >> 5;
#pragma unroll
        for (int i = 0; i < 4; ++i)
            shW[(ty + i * 8) * 33 + tx] =
                Wo[(size_t)(tj * 32 + ty + i * 8) * 256 + ti * 32 + tx];
        __syncthreads();
#pragma unroll
        for (int i = 0; i < 4; ++i)
            wot[(size_t)(ti * 32 + ty + i * 8) * 256 + tj * 32 + tx] =
                f2b(shW[tx * 33 + ty + i * 8]);
    } else if (bid < 268){
        int t = bid - 256;
        int b = t / 3, mat = t % 3;
        float S = 0.f, S2 = 0.f;
        for (int h = 0; h < 64; ++h){
            S += psum[(b * 64 + h) * 256 + tid]; S2 += psum2[(b * 64 + h) * 256 + tid];
        }
        float m = S * (1.f / 4096.f);
        float v = S2 * (1.f / 4096.f) - m * m;
        shM[tid] = m * rsqrtf(v + 1e-5f);
        __syncthreads();
        const float* W  = (mat == 0) ? Wq : (mat == 1) ? Wk : Wv;
        const float* bb = (mat == 0) ? bq : (mat == 1) ? bk : bv;
        float qs = (mat == 0) ? 0.0625f : 1.0f;
        float acc = 0.f;
        for (int c = 0; c < 256; ++c)
            acc += shM[c] * W[(size_t)c * 256 + tid];
        biasp[b * 768 + mat * 256 + tid] = (bb[tid] - acc) * qs;
    } else {
        int t = bid - 268;                 // 64 blocks x 32 rows = 2048 rows
        int b = t / 16, seg = t % 16;
        float S = 0.f;
        for (int h = 0; h < 64; ++h) S += psum[(b * 64 + h) * 256 + tid];
        ushort mb = f2b(S * (1.f / 4096.f));
        for (int r = 0; r < 32; ++r){
            int j = seg * 32 + r;          // 0..511 within batch b
            int row;
            if (j < 260){
                int h66, w66;
                if (j < 66)       { h66 = 0;       w66 = j; }
                else if (j < 132) { h66 = 65;      w66 = j - 66; }
                else if (j < 196) { h66 = j - 131; w66 = 0; }
                else              { h66 = j - 195; w66 = 65; }
                row = h66 * 66 + w66;
            } else row = 4356 + (j - 260);
            xt[((size_t)b * MB + row) * 256 + tid] = mb;
        }
    }
}

// ------------- QKV GEMM: 256x256 tile, BK=64, 8 waves, counted vmcnt --------
__global__ __launch_bounds__(512, 1)
void gemm_qkv(const ushort* __restrict__ X, const ushort* __restrict__ Y,
              const float* __restrict__ bias, ushort* __restrict__ zb){
    __shared__ ushort ldsA[2][256 * 64];
    __shared__ ushort ldsB[2][256 * 64];
    const int tid  = threadIdx.x;
    const int lane = tid & 63;
    const int wid  = tid >> 6;            // 0..7
    const int wm   = wid >> 2;            // 0..1 : rows wm*128
    const int wn   = wid & 3;             // 0..3 : cols wn*64
    const int id    = blockIdx.x;
    const int mtile = id % 72, ntile = id / 72;   // m-fastest dispatch
    const int x0 = mtile * 256, y0 = ntile * 256;
    const int bsel = x0 / MB;
    const ushort* Yb   = Y + ((size_t)bsel * QKVS + y0) * 256;
    const float* biasb = bias + bsel * 768;

    auto stage = [&](int buf, int k0){
#pragma unroll
        for (int i = 0; i < 4; ++i){
            int f   = i * 512 + tid;          // chunk 0..2047
            int row = f >> 3, cp = f & 7;
            int cs  = cp ^ (row & 7);
            const ushort* ga = X  + (size_t)(x0 + row) * KDIM + k0 + cs * 8;
            const ushort* gb = Yb + (size_t)row        * KDIM + k0 + cs * 8;
            __builtin_amdgcn_global_load_lds(
                (const __attribute__((address_space(1))) void*)ga,
                (__attribute__((address_space(3))) void*)&ldsA[buf][f * 8], 16, 0, 0);
            __builtin_amdgcn_global_load_lds(
                (const __attribute__((address_space(1))) void*)gb,
                (__attribute__((address_space(3))) void*)&ldsB[buf][f * 8], 16, 0, 0);
        }
    };

    f32x4 acc[8][4];
#pragma unroll
    for (int i = 0; i < 8; ++i)
#pragma unroll
        for (int j = 0; j < 4; ++j) acc[i][j] = f32x4{0.f, 0.f, 0.f, 0.f};

    stage(0, 0);
    stage(1, 64);
#pragma unroll
    for (int t = 0; t < 4; ++t){
        if (t < 3) asm volatile("s_waitcnt vmcnt(8)" ::: "memory");
        else       asm volatile("s_waitcnt vmcnt(0)" ::: "memory");
        __builtin_amdgcn_sched_barrier(0);
        __builtin_amdgcn_s_barrier();
        __builtin_amdgcn_sched_barrier(0);
        const int buf = t & 1;
        __builtin_amdgcn_s_setprio(1);
#pragma unroll
        for (int kk = 0; kk < 2; ++kk){
            bf16x8 af[8], bf[4];
#pragma unroll
            for (int fm = 0; fm < 8; ++fm){
                int r = wm * 128 + fm * 16 + (lane & 15);
                int c = kk * 4 + (lane >> 4);
                af[fm] = *(const bf16x8*)&ldsA[buf][(r * 8 + (c ^ (r & 7))) * 8];
            }
#pragma unroll
            for (int fn = 0; fn < 4; ++fn){
                int r = wn * 64 + fn * 16 + (lane & 15);
                int c = kk * 4 + (lane >> 4);
                bf[fn] = *(const bf16x8*)&ldsB[buf][(r * 8 + (c ^ (r & 7))) * 8];
            }
#pragma unroll
            for (int fm = 0; fm < 8; ++fm)
#pragma unroll
                for (int fn = 0; fn < 4; ++fn)
                    acc[fm][fn] = __builtin_amdgcn_mfma_f32_16x16x32_bf16(
                        af[fm], bf[fn], acc[fm][fn], 0, 0, 0);
        }
        __builtin_amdgcn_s_setprio(0);
        __builtin_amdgcn_sched_barrier(0);
        __builtin_amdgcn_s_barrier();
        __builtin_amdgcn_sched_barrier(0);
        if (t < 2) stage(t & 1, (t + 2) * 64);
    }

#pragma unroll
    for (int fm = 0; fm < 8; ++fm){
#pragma unroll
        for (int fn = 0; fn < 4; ++fn){
            int xr = x0 + wm * 128 + fm * 16 + ((lane >> 4) << 2);
            int yc = y0 + wn * 64 + fn * 16 + (lane & 15);
            float bv = biasb[yc];
#pragma unroll
            for (int r = 0; r < 4; ++r)
                zb[(size_t)(xr + r) * QKVS + yc] = f2b(acc[fm][fn][r] + bv);
        }
    }
}

// ------ fused 3x3-window attention + output GEMM: block = one (b,h) row -----
// phase 1: 8 waves x 8 pixels -> ctx bf16 in swizzled LDS [64 pix][256 ch]
// phase 2: out[ch][pix] = WoT[ch][:] . ctx[pix][:] + bo[ch], NCHW fp32 store
__global__ __launch_bounds__(512, 1)
void attn_out(const ushort* __restrict__ qkv, const ushort* __restrict__ wot,
              const float* __restrict__ bo, float* __restrict__ out){
    __shared__ ushort ctx[64 * 256];
    const int tid = threadIdx.x, lane = tid & 63, wid = tid >> 6;
    const int b = blockIdx.x >> 6, h = blockIdx.x & 63;
    const uint base = (uint)b * MB;

    // ---- phase 1: attention ----
#pragma unroll 1
    for (int j = 0; j < 8; ++j){
        const int w = wid * 8 + j;
        uint crow = base + (uint)(h + 1) * 66 + (w + 1);
        ushort4 q4 = *(const ushort4*)(qkv + (size_t)crow * QKVS + lane * 4);
        float q0 = b2f(q4.x), q1 = b2f(q4.y), q2 = b2f(q4.z), q3 = b2f(q4.w);

        float lg[9];
        uint rows[9];
#pragma unroll
        for (int n = 0; n < 9; ++n){
            int dh = n / 3, dw = n % 3;
            uint row = base + (uint)(h + dh) * 66 + (w + dw);
            rows[n] = row;
            ushort4 k4 = *(const ushort4*)(qkv + (size_t)row * QKVS + 256 + lane * 4);
            float d = q0 * b2f(k4.x) + q1 * b2f(k4.y) + q2 * b2f(k4.z) + q3 * b2f(k4.w);
#pragma unroll
            for (int off = 32; off; off >>= 1) d += __shfl_xor(d, off);
            lg[n] = d;
        }
        float m = lg[0];
#pragma unroll
        for (int n = 1; n < 9; ++n) m = fmaxf(m, lg[n]);
        float e[9], s = 0.f;
#pragma unroll
        for (int n = 0; n < 9; ++n){ e[n] = __expf(lg[n] - m); s += e[n]; }
        float inv = 1.f / s;

        float c0 = 0.f, c1 = 0.f, c2 = 0.f, c3 = 0.f;
#pragma unroll
        for (int n = 0; n < 9; ++n){
            float a = e[n] * inv;
            ushort4 v4 = *(const ushort4*)(qkv + (size_t)rows[n] * QKVS + 512 + lane * 4);
            c0 += a * b2f(v4.x); c1 += a * b2f(v4.y);
            c2 += a * b2f(v4.z); c3 += a * b2f(v4.w);
        }
        ushort4 o; o.x = f2b(c0); o.y = f2b(c1); o.z = f2b(c2); o.w = f2b(c3);
        // chunk-XOR swizzled store: chunk = lane>>1, half = lane&1
        *(ushort4*)&ctx[w * 256 + (((lane >> 1) ^ (w & 7)) * 8) + (lane & 1) * 4] = o;
    }
    __syncthreads();

    // ---- phase 2: out GEMM (M=256 ch x N=64 pix x K=256) ----
    const int wmi = wid >> 1, wni = wid & 1;
    f32x4 acc[4][2];
#pragma unroll
    for (int i = 0; i < 4; ++i){ acc[i][0] = f32x4{0,0,0,0}; acc[i][1] = f32x4{0,0,0,0}; }

#pragma unroll
    for (int kk = 0; kk < 8; ++kk){
        bf16x8 af[4], bf[2];
        const int c = kk * 4 + (lane >> 4);
#pragma unroll
        for (int fm = 0; fm < 4; ++fm){
            int r = wmi * 64 + fm * 16 + (lane & 15);
            af[fm] = *(const bf16x8*)(wot + (size_t)r * 256 + c * 8);
        }
#pragma unroll
        for (int fn = 0; fn < 2; ++fn){
            int p = wni * 32 + fn * 16 + (lane & 15);
            bf[fn] = *(const bf16x8*)&ctx[p * 256 + (c ^ (p & 7)) * 8];
        }
#pragma unroll
        for (int fm = 0; fm < 4; ++fm)
#pragma unroll
            for (int fn = 0; fn < 2; ++fn)
                acc[fm][fn] = __builtin_amdgcn_mfma_f32_16x16x32_bf16(
                    af[fm], bf[fn], acc[fm][fn], 0, 0, 0);
    }

#pragma unroll
    for (int fm = 0; fm < 4; ++fm){
#pragma unroll
        for (int fn = 0; fn < 2; ++fn){
            int ch0  = wmi * 64 + fm * 16 + ((lane >> 4) << 2);
            int wpix = wni * 32 + fn * 16 + (lane & 15);
#pragma unroll
            for (int r = 0; r < 4; ++r){
                int ch = ch0 + r;
                out[((size_t)(b * 256 + ch)) * 4096 + h * 64 + wpix] =
                    acc[fm][fn][r] + bo[ch];
            }
        }
    }
}

// ---------------------------------------------------------------------------
extern "C" void kernel_launch(void* const* d_in, const int* in_sizes, int n_in,
                              void* d_out, int out_size, void* d_ws, size_t ws_size,
                              hipStream_t stream){
    const float* x  = (const float*)d_in[0];
    const float* Wq = (const float*)d_in[1];
    const float* bq = (const float*)d_in[2];
    const float* Wk = (const float*)d_in[3];
    const float* bk = (const float*)d_in[4];
    const float* Wv = (const float*)d_in[5];
    const float* bv = (const float*)d_in[6];
    const float* Wo = (const float*)d_in[7];
    const float* bo = (const float*)d_in[8];
    float* out = (float*)d_out;

    char* ws = (char*)d_ws;
    ushort* wtq    = (ushort*)(ws);                // [4][768][256] bf16
    ushort* wot    = (ushort*)(ws + 1572864);      // [256][256] bf16
    float*  biasp  = (float*) (ws + 1703936);      // [4][768]
    float*  psum   = (float*) (ws + 1716224);      // [256][256]
    float*  psum2  = (float*) (ws + 1978368);      // [256][256]
    ushort* xt     = (ushort*)(ws + 2240512);      // [MTOT][256] bf16
    ushort* qkv    = (ushort*)(ws + 11677696);     // [MTOT][768] bf16

    ln_fuse<<<512, 256, 0, stream>>>(x, xt, psum, psum2);
    prep2<<<332, 256, 0, stream>>>(Wq, bq, Wk, bk, Wv, bv, Wo,
                                   psum, psum2, wtq, wot, biasp, xt);

    gemm_qkv<<<216, 512, 0, stream>>>(xt, wtq, biasp, qkv);   // 72 M x 3 N tiles

    attn_out<<<256, 512, 0, stream>>>(qkv, wot, bo, out);
}

// Round 7
// 63.479 us; speedup vs baseline: 1.2928x; 1.2928x over previous
//
#include <hip/hip_runtime.h>
#include <hip/hip_bf16.h>
#include <stdint.h>

typedef __bf16 bf16x8 __attribute__((ext_vector_type(8)));
typedef float f32x4 __attribute__((ext_vector_type(4)));

#define KDIM 256
#define NPIX 16384       // 4*64*64 center pixels (no pad domain)
#define QKVS 768         // fused q/k/v row stride

__device__ __forceinline__ float b2f(ushort u){
    union { float f; uint32_t i; } x; x.i = ((uint32_t)u) << 16; return x.f;
}
__device__ __forceinline__ ushort f2b(float f){
    uint32_t u = __float_as_uint(f);
    uint32_t r = (u + 0x7fffu + ((u >> 16) & 1u)) >> 16;
    return (ushort)r;
}

// --------- P1: single x pass -> bf16 CL transpose + fp32 LN partials --------
// 512 blocks: (b, h, c-half). Reads x[b, ch:ch+128, h, :] coalesced, LDS
// transpose, writes xt[pix][c] (32KB contiguous per block), emits psum/psum2.
__global__ __launch_bounds__(256)
void ln_fuse(const float* __restrict__ x, ushort* __restrict__ xt,
             float* __restrict__ psum, float* __restrict__ psum2){
    __shared__ ushort sh[128 * 68];
    __shared__ float ssum[16 * 132], ssum2[16 * 132];
    const int bid = blockIdx.x;
    const int b = bid >> 7, rem = bid & 127, h = rem >> 1, ch = (rem & 1) * 128;
    const int tid = threadIdx.x;
    const int csub = tid >> 4, w4 = tid & 15;
#pragma unroll
    for (int i = 0; i < 8; ++i){
        int c = csub + 16 * i;            // local channel 0..127
        float4 v = *(const float4*)(x + ((size_t)(b * 256 + ch + c)) * 4096
                                      + h * 64 + w4 * 4);
        ushort4 u; u.x = f2b(v.x); u.y = f2b(v.y); u.z = f2b(v.z); u.w = f2b(v.w);
        *(ushort4*)&sh[c * 68 + w4 * 4] = u;
        ssum [w4 * 132 + c] = v.x + v.y + v.z + v.w;
        ssum2[w4 * 132 + c] = v.x * v.x + v.y * v.y + v.z * v.z + v.w * v.w;
    }
    __syncthreads();
    if (tid < 128){
        float S = 0.f, S2 = 0.f;
#pragma unroll
        for (int j = 0; j < 16; ++j){ S += ssum[j * 132 + tid]; S2 += ssum2[j * 132 + tid]; }
        psum [(b * 64 + h) * 256 + ch + tid] = S;
        psum2[(b * 64 + h) * 256 + ch + tid] = S2;
    }
    const int c16 = tid & 15, w16 = tid >> 4;
#pragma unroll
    for (int p = 0; p < 4; ++p){
        int w = p * 16 + w16;
        union { ushort u[8]; uint4 v; } r;
#pragma unroll
        for (int j = 0; j < 8; ++j) r.u[j] = sh[(c16 * 8 + j) * 68 + w];
        size_t row = (size_t)(b * 4096 + h * 64 + w);
        *(uint4*)(xt + row * 256 + ch + c16 * 8) = r.v;
    }
}

// --------- P2: per-b scaled weights + folded bias + pad row (block-range) ---
// [0,192):   qkv weight transpose, 4 b-copies scaled by rv[b,k] (q also /16)
// [192,256): Wo transpose (unscaled)
// [256,268): folded bias: biasp[b][n] = qs*(bias[n] - sum_c m*rv*W[c,n])
// 268:       pad qkv row: k = bf16(bk), v = bf16(bv)  (reference zero-pad)
__global__ __launch_bounds__(256)
void prep2(const float* __restrict__ Wq, const float* __restrict__ bq,
           const float* __restrict__ Wk, const float* __restrict__ bk,
           const float* __restrict__ Wv, const float* __restrict__ bv,
           const float* __restrict__ Wo,
           const float* __restrict__ psum, const float* __restrict__ psum2,
           ushort* __restrict__ wtq, ushort* __restrict__ wot,
           float* __restrict__ biasp, ushort* __restrict__ qkv){
    __shared__ float shW[32 * 33];
    __shared__ float shS[8 * 32], shS2[8 * 32], shRV[4 * 32], shM[256];
    const int bid = blockIdx.x, tid = threadIdx.x;
    if (bid < 192){
        int mat = bid / 64, tile = bid % 64;
        int ti = tile & 7, tj = tile >> 3;
        {
            int kk = tid & 31, idx = tid >> 5;        // idx: b*2 + h-half
            int b = idx >> 1, h0 = (idx & 1) * 32;
            float S = 0.f, S2 = 0.f;
            for (int r = 0; r < 32; ++r){
                int off = (b * 64 + h0 + r) * 256 + tj * 32 + kk;
                S += psum[off]; S2 += psum2[off];
            }
            shS[idx * 32 + kk] = S; shS2[idx * 32 + kk] = S2;
        }
        __syncthreads();
        if (tid < 128){
            int b = tid >> 5, kk = tid & 31;
            float S  = shS [(b * 2) * 32 + kk] + shS [(b * 2 + 1) * 32 + kk];
            float S2 = shS2[(b * 2) * 32 + kk] + shS2[(b * 2 + 1) * 32 + kk];
            float m = S * (1.f / 4096.f);
            float v = S2 * (1.f / 4096.f) - m * m;
            shRV[b * 32 + kk] = rsqrtf(v + 1e-5f);
        }
        const float* src = (mat == 0) ? Wq : (mat == 1) ? Wk : Wv;
        float qs = (mat == 0) ? 0.0625f : 1.0f;
        int tx = tid & 31, ty = tid >> 5;
#pragma unroll
        for (int i = 0; i < 4; ++i)
            shW[(ty + i * 8) * 33 + tx] =
                src[(size_t)(tj * 32 + ty + i * 8) * 256 + ti * 32 + tx] * qs;
        __syncthreads();
#pragma unroll
        for (int b = 0; b < 4; ++b){
            float rv = shRV[b * 32 + tx];
#pragma unroll
            for (int i = 0; i < 4; ++i){
                int n = mat * 256 + ti * 32 + ty + i * 8;
                wtq[((size_t)b * 768 + n) * 256 + tj * 32 + tx] =
                    f2b(shW[tx * 33 + ty + i * 8] * rv);
            }
        }
    } else if (bid < 256){
        int tile = bid - 192;
        int ti = tile & 7, tj = tile >> 3;
        int tx = tid & 31, ty = tid >> 5;
#pragma unroll
        for (int i = 0; i < 4; ++i)
            shW[(ty + i * 8) * 33 + tx] =
                Wo[(size_t)(tj * 32 + ty + i * 8) * 256 + ti * 32 + tx];
        __syncthreads();
#pragma unroll
        for (int i = 0; i < 4; ++i)
            wot[(size_t)(ti * 32 + ty + i * 8) * 256 + tj * 32 + tx] =
                f2b(shW[tx * 33 + ty + i * 8]);
    } else if (bid < 268){
        int t = bid - 256;
        int b = t / 3, mat = t % 3;
        float S = 0.f, S2 = 0.f;
        for (int h = 0; h < 64; ++h){
            S += psum[(b * 64 + h) * 256 + tid]; S2 += psum2[(b * 64 + h) * 256 + tid];
        }
        float m = S * (1.f / 4096.f);
        float v = S2 * (1.f / 4096.f) - m * m;
        shM[tid] = m * rsqrtf(v + 1e-5f);
        __syncthreads();
        const float* W  = (mat == 0) ? Wq : (mat == 1) ? Wk : Wv;
        const float* bb = (mat == 0) ? bq : (mat == 1) ? bk : bv;
        float qs = (mat == 0) ? 0.0625f : 1.0f;
        float acc = 0.f;
        for (int c = 0; c < 256; ++c)
            acc += shM[c] * W[(size_t)c * 256 + tid];
        biasp[b * 768 + mat * 256 + tid] = (bb[tid] - acc) * qs;
    } else {
        // pad row at qkv[NPIX]: q part zero, k = bf16(bk), v = bf16(bv)
        ushort* pad = qkv + (size_t)NPIX * QKVS;
        pad[tid]       = 0;
        pad[256 + tid] = f2b(bk[tid]);
        pad[512 + tid] = f2b(bv[tid]);
    }
}

// ------------- QKV GEMM: m97-style 128x128 tile, BK=64, 4 waves -------------
// qkv[pix][n] = dot(xt[pix][:], wtq[b][n][:]) + biasp[b][n], b = pix >> 12
__global__ __launch_bounds__(256, 2)
void gemm_qkv(const ushort* __restrict__ X, const ushort* __restrict__ Y,
              const float* __restrict__ bias, ushort* __restrict__ zb){
    __shared__ ushort ldsX[2][128 * 64];
    __shared__ ushort ldsY[2][128 * 64];
    const int tid  = threadIdx.x;
    const int lane = tid & 63;
    const int wid  = tid >> 6;
    const int wm   = wid >> 1, wn = wid & 1;
    const int x0   = blockIdx.x * 128, y0 = blockIdx.y * 128;
    const int bsel = x0 >> 12;
    const ushort* Yb   = Y + (size_t)bsel * QKVS * 256;
    const float* biasb = bias + bsel * QKVS;

    // T2 chunk swizzle: LDS dest linear, global source chunk pre-swizzled,
    // reads apply the same XOR (16B-chunk granularity, 8 chunks/row).
    auto stage = [&](int buf, int k0){
#pragma unroll
        for (int i = 0; i < 4; ++i){
            int f   = i * 256 + tid;          // dest 16B-chunk index
            int row = f >> 3, cp = f & 7;
            int cs  = cp ^ (row & 7);         // source chunk (involution)
            const ushort* gx = X  + (size_t)(x0 + row) * KDIM + k0 + cs * 8;
            const ushort* gy = Yb + (size_t)(y0 + row) * KDIM + k0 + cs * 8;
            __builtin_amdgcn_global_load_lds(
                (const __attribute__((address_space(1))) void*)gx,
                (__attribute__((address_space(3))) void*)&ldsX[buf][f * 8], 16, 0, 0);
            __builtin_amdgcn_global_load_lds(
                (const __attribute__((address_space(1))) void*)gy,
                (__attribute__((address_space(3))) void*)&ldsY[buf][f * 8], 16, 0, 0);
        }
    };

    f32x4 acc[4][4];
#pragma unroll
    for (int i = 0; i < 4; ++i)
#pragma unroll
        for (int j = 0; j < 4; ++j) acc[i][j] = f32x4{0.f, 0.f, 0.f, 0.f};

    stage(0, 0);
    int buf = 0;
    for (int t = 0; t < 4; ++t){            // K = 256 = 4 * 64
        __syncthreads();
        if (t < 3) stage(buf ^ 1, (t + 1) * 64);
#pragma unroll
        for (int kk = 0; kk < 2; ++kk){
            bf16x8 xa[4], yb[4];
#pragma unroll
            for (int fm = 0; fm < 4; ++fm){
                int r = wm * 64 + fm * 16 + (lane & 15);
                int c = kk * 4 + (lane >> 4);
                xa[fm] = *(const bf16x8*)&ldsX[buf][(r * 8 + (c ^ (r & 7))) * 8];
            }
#pragma unroll
            for (int fn = 0; fn < 4; ++fn){
                int r = wn * 64 + fn * 16 + (lane & 15);
                int c = kk * 4 + (lane >> 4);
                yb[fn] = *(const bf16x8*)&ldsY[buf][(r * 8 + (c ^ (r & 7))) * 8];
            }
#pragma unroll
            for (int fm = 0; fm < 4; ++fm)
#pragma unroll
                for (int fn = 0; fn < 4; ++fn)
                    acc[fm][fn] = __builtin_amdgcn_mfma_f32_16x16x32_bf16(
                        xa[fm], yb[fn], acc[fm][fn], 0, 0, 0);
        }
        buf ^= 1;
    }

#pragma unroll
    for (int fm = 0; fm < 4; ++fm){
#pragma unroll
        for (int fn = 0; fn < 4; ++fn){
            int xr = x0 + wm * 64 + fm * 16 + ((lane >> 4) << 2);
            int yc = y0 + wn * 64 + fn * 16 + (lane & 15);
            float bv = biasb[yc];
#pragma unroll
            for (int r = 0; r < 4; ++r)
                zb[(size_t)(xr + r) * QKVS + yc] = f2b(acc[fm][fn][r] + bv);
        }
    }
}

// ------------------- 3x3 window attention: one wave per pixel ---------------
// out-of-bounds neighbors read the pad row (k=bk, v=bv) at qkv[NPIX]
__global__ __launch_bounds__(256)
void attn_win(const ushort* __restrict__ qkv, ushort* __restrict__ ctx){
    int pix  = blockIdx.x * 4 + (threadIdx.x >> 6);
    int lane = threadIdx.x & 63;
    int b = pix >> 12, hw = pix & 4095;
    int h = hw >> 6, w = hw & 63;
    const size_t PADOFF = (size_t)NPIX * QKVS;

    ushort4 q4 = *(const ushort4*)(qkv + (size_t)pix * QKVS + lane * 4);
    float q0 = b2f(q4.x), q1 = b2f(q4.y), q2 = b2f(q4.z), q3 = b2f(q4.w);

    float lg[9];
    size_t roff[9];
#pragma unroll
    for (int n = 0; n < 9; ++n){
        int nh = h + n / 3 - 1, nw = w + n % 3 - 1;
        bool ok = ((unsigned)nh < 64u) & ((unsigned)nw < 64u);
        roff[n] = ok ? (size_t)((b << 12) + (nh << 6) + nw) * QKVS : PADOFF;
        ushort4 k4 = *(const ushort4*)(qkv + roff[n] + 256 + lane * 4);
        float d = q0 * b2f(k4.x) + q1 * b2f(k4.y) + q2 * b2f(k4.z) + q3 * b2f(k4.w);
#pragma unroll
        for (int off = 32; off; off >>= 1) d += __shfl_xor(d, off);
        lg[n] = d;
    }
    float m = lg[0];
#pragma unroll
    for (int n = 1; n < 9; ++n) m = fmaxf(m, lg[n]);
    float e[9], s = 0.f;
#pragma unroll
    for (int n = 0; n < 9; ++n){ e[n] = __expf(lg[n] - m); s += e[n]; }
    float inv = 1.f / s;

    float c0 = 0.f, c1 = 0.f, c2 = 0.f, c3 = 0.f;
#pragma unroll
    for (int n = 0; n < 9; ++n){
        float a = e[n] * inv;
        ushort4 v4 = *(const ushort4*)(qkv + roff[n] + 512 + lane * 4);
        c0 += a * b2f(v4.x); c1 += a * b2f(v4.y);
        c2 += a * b2f(v4.z); c3 += a * b2f(v4.w);
    }
    ushort4 o; o.x = f2b(c0); o.y = f2b(c1); o.z = f2b(c2); o.w = f2b(c3);
    *(ushort4*)(ctx + (size_t)pix * 256 + lane * 4) = o;
}

// ------------- out GEMM (128x128, NCHW fp32 epilogue) -----------------------
__global__ __launch_bounds__(256, 2)
void gemm_out(const ushort* __restrict__ X, const ushort* __restrict__ Y,
              const float* __restrict__ bias, float* __restrict__ zf){
    __shared__ ushort ldsX[2][128 * 64];
    __shared__ ushort ldsY[2][128 * 64];
    const int tid  = threadIdx.x;
    const int lane = tid & 63;
    const int wid  = tid >> 6;
    const int wm   = wid >> 1, wn = wid & 1;
    const int x0   = blockIdx.x * 128, y0 = blockIdx.y * 128;

    auto stage = [&](int buf, int k0){
#pragma unroll
        for (int i = 0; i < 4; ++i){
            int f   = i * 256 + tid;
            int row = f >> 3, cp = f & 7;
            int cs  = cp ^ (row & 7);
            const ushort* gx = X + (size_t)(x0 + row) * KDIM + k0 + cs * 8;
            const ushort* gy = Y + (size_t)(y0 + row) * KDIM + k0 + cs * 8;
            __builtin_amdgcn_global_load_lds(
                (const __attribute__((address_space(1))) void*)gx,
                (__attribute__((address_space(3))) void*)&ldsX[buf][f * 8], 16, 0, 0);
            __builtin_amdgcn_global_load_lds(
                (const __attribute__((address_space(1))) void*)gy,
                (__attribute__((address_space(3))) void*)&ldsY[buf][f * 8], 16, 0, 0);
        }
    };

    f32x4 acc[4][4];
#pragma unroll
    for (int i = 0; i < 4; ++i)
#pragma unroll
        for (int j = 0; j < 4; ++j) acc[i][j] = f32x4{0.f, 0.f, 0.f, 0.f};

    stage(0, 0);
    int buf = 0;
    for (int t = 0; t < 4; ++t){
        __syncthreads();
        if (t < 3) stage(buf ^ 1, (t + 1) * 64);
#pragma unroll
        for (int kk = 0; kk < 2; ++kk){
            bf16x8 xa[4], yb[4];
#pragma unroll
            for (int fm = 0; fm < 4; ++fm){
                int r = wm * 64 + fm * 16 + (lane & 15);
                int c = kk * 4 + (lane >> 4);
                xa[fm] = *(const bf16x8*)&ldsX[buf][(r * 8 + (c ^ (r & 7))) * 8];
            }
#pragma unroll
            for (int fn = 0; fn < 4; ++fn){
                int r = wn * 64 + fn * 16 + (lane & 15);
                int c = kk * 4 + (lane >> 4);
                yb[fn] = *(const bf16x8*)&ldsY[buf][(r * 8 + (c ^ (r & 7))) * 8];
            }
#pragma unroll
            for (int fm = 0; fm < 4; ++fm)
#pragma unroll
                for (int fn = 0; fn < 4; ++fn)
                    acc[fm][fn] = __builtin_amdgcn_mfma_f32_16x16x32_bf16(
                        xa[fm], yb[fn], acc[fm][fn], 0, 0, 0);
        }
        buf ^= 1;
    }

#pragma unroll
    for (int fm = 0; fm < 4; ++fm){
#pragma unroll
        for (int fn = 0; fn < 4; ++fn){
            int xr = x0 + wm * 64 + fm * 16 + ((lane >> 4) << 2);
            int yc = y0 + wn * 64 + fn * 16 + (lane & 15);
            int bpix = yc >> 12, hw = yc & 4095;
#pragma unroll
            for (int r = 0; r < 4; ++r){
                int ch = xr + r;
                zf[((size_t)(bpix * 256 + ch)) * 4096 + hw] =
                    acc[fm][fn][r] + bias[ch];
            }
        }
    }
}

// ---------------------------------------------------------------------------
extern "C" void kernel_launch(void* const* d_in, const int* in_sizes, int n_in,
                              void* d_out, int out_size, void* d_ws, size_t ws_size,
                              hipStream_t stream){
    const float* x  = (const float*)d_in[0];
    const float* Wq = (const float*)d_in[1];
    const float* bq = (const float*)d_in[2];
    const float* Wk = (const float*)d_in[3];
    const float* bk = (const float*)d_in[4];
    const float* Wv = (const float*)d_in[5];
    const float* bv = (const float*)d_in[6];
    const float* Wo = (const float*)d_in[7];
    const float* bo = (const float*)d_in[8];
    float* out = (float*)d_out;

    char* ws = (char*)d_ws;
    ushort* wtq    = (ushort*)(ws);                // [4][768][256] bf16
    ushort* wot    = (ushort*)(ws + 1572864);      // [256][256] bf16
    float*  biasp  = (float*) (ws + 1703936);      // [4][768]
    float*  psum   = (float*) (ws + 1716224);      // [256][256]
    float*  psum2  = (float*) (ws + 1978368);      // [256][256]
    ushort* xt     = (ushort*)(ws + 2240512);      // [NPIX][256] bf16
    ushort* qkv    = (ushort*)(ws + 10629120);     // [NPIX+1][768] bf16 (+pad row)
    ushort* ctx    = (ushort*)(ws + 35796480);     // [NPIX][256] bf16

    ln_fuse<<<512, 256, 0, stream>>>(x, xt, psum, psum2);
    prep2<<<269, 256, 0, stream>>>(Wq, bq, Wk, bk, Wv, bv, Wo,
                                   psum, psum2, wtq, wot, biasp, qkv);

    dim3 g1(128, 6);   // M-tiles x N-tiles
    gemm_qkv<<<g1, 256, 0, stream>>>(xt, wtq, biasp, qkv);

    attn_win<<<4096, 256, 0, stream>>>(qkv, ctx);

    dim3 g2(2, 128);
    gemm_out<<<g2, 256, 0, stream>>>(wot, ctx, bo, out);
}

// Round 8
// 58.042 us; speedup vs baseline: 1.4139x; 1.0937x over previous
//
#include <hip/hip_runtime.h>
#include <hip/hip_bf16.h>
#include <stdint.h>

typedef __bf16 bf16x8 __attribute__((ext_vector_type(8)));
typedef float f32x4 __attribute__((ext_vector_type(4)));

#define KDIM 256
#define NPIX 16384       // 4*64*64 center pixels (no pad domain)
#define QKVS 768         // fused q/k/v row stride

__device__ __forceinline__ float b2f(ushort u){
    union { float f; uint32_t i; } x; x.i = ((uint32_t)u) << 16; return x.f;
}
__device__ __forceinline__ ushort f2b(float f){
    uint32_t u = __float_as_uint(f);
    uint32_t r = (u + 0x7fffu + ((u >> 16) & 1u)) >> 16;
    return (ushort)r;
}
__device__ __forceinline__ void unpack2(uint d, float& lo, float& hi){
    lo = __uint_as_float(d << 16);
    hi = __uint_as_float(d & 0xffff0000u);
}
__device__ __forceinline__ uint cvtpk(float lo, float hi){
    uint r;
    asm volatile("v_cvt_pk_bf16_f32 %0, %1, %2" : "=v"(r) : "v"(lo), "v"(hi));
    return r;
}

// --------- P1: single x pass -> bf16 CL transpose + fp32 LN partials --------
__global__ __launch_bounds__(256)
void ln_fuse(const float* __restrict__ x, ushort* __restrict__ xt,
             float* __restrict__ psum, float* __restrict__ psum2){
    __shared__ ushort sh[128 * 68];
    __shared__ float ssum[16 * 132], ssum2[16 * 132];
    const int bid = blockIdx.x;
    const int b = bid >> 7, rem = bid & 127, h = rem >> 1, ch = (rem & 1) * 128;
    const int tid = threadIdx.x;
    const int csub = tid >> 4, w4 = tid & 15;
#pragma unroll
    for (int i = 0; i < 8; ++i){
        int c = csub + 16 * i;            // local channel 0..127
        float4 v = *(const float4*)(x + ((size_t)(b * 256 + ch + c)) * 4096
                                      + h * 64 + w4 * 4);
        ushort4 u; u.x = f2b(v.x); u.y = f2b(v.y); u.z = f2b(v.z); u.w = f2b(v.w);
        *(ushort4*)&sh[c * 68 + w4 * 4] = u;
        ssum [w4 * 132 + c] = v.x + v.y + v.z + v.w;
        ssum2[w4 * 132 + c] = v.x * v.x + v.y * v.y + v.z * v.z + v.w * v.w;
    }
    __syncthreads();
    if (tid < 128){
        float S = 0.f, S2 = 0.f;
#pragma unroll
        for (int j = 0; j < 16; ++j){ S += ssum[j * 132 + tid]; S2 += ssum2[j * 132 + tid]; }
        psum [(b * 64 + h) * 256 + ch + tid] = S;
        psum2[(b * 64 + h) * 256 + ch + tid] = S2;
    }
    const int c16 = tid & 15, w16 = tid >> 4;
#pragma unroll
    for (int p = 0; p < 4; ++p){
        int w = p * 16 + w16;
        union { ushort u[8]; uint4 v; } r;
#pragma unroll
        for (int j = 0; j < 8; ++j) r.u[j] = sh[(c16 * 8 + j) * 68 + w];
        size_t row = (size_t)(b * 4096 + h * 64 + w);
        *(uint4*)(xt + row * 256 + ch + c16 * 8) = r.v;
    }
}

// --------- P2: per-b scaled weights + folded bias + pad row (block-range) ---
__global__ __launch_bounds__(256)
void prep2(const float* __restrict__ Wq, const float* __restrict__ bq,
           const float* __restrict__ Wk, const float* __restrict__ bk,
           const float* __restrict__ Wv, const float* __restrict__ bv,
           const float* __restrict__ Wo,
           const float* __restrict__ psum, const float* __restrict__ psum2,
           ushort* __restrict__ wtq, ushort* __restrict__ wot,
           float* __restrict__ biasp, ushort* __restrict__ qkv){
    __shared__ float shW[32 * 33];
    __shared__ float shS[8 * 32], shS2[8 * 32], shRV[4 * 32], shM[256];
    const int bid = blockIdx.x, tid = threadIdx.x;
    if (bid < 192){
        int mat = bid / 64, tile = bid % 64;
        int ti = tile & 7, tj = tile >> 3;
        {
            int kk = tid & 31, idx = tid >> 5;        // idx: b*2 + h-half
            int b = idx >> 1, h0 = (idx & 1) * 32;
            float S = 0.f, S2 = 0.f;
            for (int r = 0; r < 32; ++r){
                int off = (b * 64 + h0 + r) * 256 + tj * 32 + kk;
                S += psum[off]; S2 += psum2[off];
            }
            shS[idx * 32 + kk] = S; shS2[idx * 32 + kk] = S2;
        }
        __syncthreads();
        if (tid < 128){
            int b = tid >> 5, kk = tid & 31;
            float S  = shS [(b * 2) * 32 + kk] + shS [(b * 2 + 1) * 32 + kk];
            float S2 = shS2[(b * 2) * 32 + kk] + shS2[(b * 2 + 1) * 32 + kk];
            float m = S * (1.f / 4096.f);
            float v = S2 * (1.f / 4096.f) - m * m;
            shRV[b * 32 + kk] = rsqrtf(v + 1e-5f);
        }
        const float* src = (mat == 0) ? Wq : (mat == 1) ? Wk : Wv;
        float qs = (mat == 0) ? 0.0625f : 1.0f;
        int tx = tid & 31, ty = tid >> 5;
#pragma unroll
        for (int i = 0; i < 4; ++i)
            shW[(ty + i * 8) * 33 + tx] =
                src[(size_t)(tj * 32 + ty + i * 8) * 256 + ti * 32 + tx] * qs;
        __syncthreads();
#pragma unroll
        for (int b = 0; b < 4; ++b){
            float rv = shRV[b * 32 + tx];
#pragma unroll
            for (int i = 0; i < 4; ++i){
                int n = mat * 256 + ti * 32 + ty + i * 8;
                wtq[((size_t)b * 768 + n) * 256 + tj * 32 + tx] =
                    f2b(shW[tx * 33 + ty + i * 8] * rv);
            }
        }
    } else if (bid < 256){
        int tile = bid - 192;
        int ti = tile & 7, tj = tile >> 3;
        int tx = tid & 31, ty = tid >> 5;
#pragma unroll
        for (int i = 0; i < 4; ++i)
            shW[(ty + i * 8) * 33 + tx] =
                Wo[(size_t)(tj * 32 + ty + i * 8) * 256 + ti * 32 + tx];
        __syncthreads();
#pragma unroll
        for (int i = 0; i < 4; ++i)
            wot[(size_t)(ti * 32 + ty + i * 8) * 256 + tj * 32 + tx] =
                f2b(shW[tx * 33 + ty + i * 8]);
    } else if (bid < 268){
        int t = bid - 256;
        int b = t / 3, mat = t % 3;
        float S = 0.f, S2 = 0.f;
        for (int h = 0; h < 64; ++h){
            S += psum[(b * 64 + h) * 256 + tid]; S2 += psum2[(b * 64 + h) * 256 + tid];
        }
        float m = S * (1.f / 4096.f);
        float v = S2 * (1.f / 4096.f) - m * m;
        shM[tid] = m * rsqrtf(v + 1e-5f);
        __syncthreads();
        const float* W  = (mat == 0) ? Wq : (mat == 1) ? Wk : Wv;
        const float* bb = (mat == 0) ? bq : (mat == 1) ? bk : bv;
        float qs = (mat == 0) ? 0.0625f : 1.0f;
        float acc = 0.f;
        for (int c = 0; c < 256; ++c)
            acc += shM[c] * W[(size_t)c * 256 + tid];
        biasp[b * 768 + mat * 256 + tid] = (bb[tid] - acc) * qs;
    } else {
        // pad row at qkv[NPIX]: q part zero, k = bf16(bk), v = bf16(bv)
        ushort* pad = qkv + (size_t)NPIX * QKVS;
        pad[tid]       = 0;
        pad[256 + tid] = f2b(bk[tid]);
        pad[512 + tid] = f2b(bv[tid]);
    }
}

// ------------- QKV GEMM: 256x256 tile, BK=64, 8 waves, counted vmcnt --------
// qkv[pix][n] = dot(xt[pix][:], wtq[b][n][:]) + biasp[b][n], b = pix >> 12
__global__ __launch_bounds__(512, 1)
void gemm_qkv(const ushort* __restrict__ X, const ushort* __restrict__ Y,
              const float* __restrict__ bias, ushort* __restrict__ zb){
    __shared__ ushort ldsA[2][256 * 64];
    __shared__ ushort ldsB[2][256 * 64];
    const int tid  = threadIdx.x;
    const int lane = tid & 63;
    const int wid  = tid >> 6;            // 0..7
    const int wm   = wid >> 2;            // 0..1 : rows wm*128
    const int wn   = wid & 3;             // 0..3 : cols wn*64
    const int id    = blockIdx.x;
    const int mtile = id & 63, ntile = id >> 6;   // m-fastest (B-panel reuse)
    const int x0 = mtile * 256, y0 = ntile * 256;
    const int bsel = x0 >> 12;
    const ushort* Yb   = Y + ((size_t)bsel * QKVS + y0) * 256;
    const float* biasb = bias + bsel * QKVS;

    auto stage = [&](int buf, int k0){
#pragma unroll
        for (int i = 0; i < 4; ++i){
            int f   = i * 512 + tid;          // chunk 0..2047
            int row = f >> 3, cp = f & 7;
            int cs  = cp ^ (row & 7);
            const ushort* ga = X  + (size_t)(x0 + row) * KDIM + k0 + cs * 8;
            const ushort* gb = Yb + (size_t)row        * KDIM + k0 + cs * 8;
            __builtin_amdgcn_global_load_lds(
                (const __attribute__((address_space(1))) void*)ga,
                (__attribute__((address_space(3))) void*)&ldsA[buf][f * 8], 16, 0, 0);
            __builtin_amdgcn_global_load_lds(
                (const __attribute__((address_space(1))) void*)gb,
                (__attribute__((address_space(3))) void*)&ldsB[buf][f * 8], 16, 0, 0);
        }
    };

    f32x4 acc[8][4];
#pragma unroll
    for (int i = 0; i < 8; ++i)
#pragma unroll
        for (int j = 0; j < 4; ++j) acc[i][j] = f32x4{0.f, 0.f, 0.f, 0.f};

    stage(0, 0);
    stage(1, 64);
#pragma unroll
    for (int t = 0; t < 4; ++t){
        if (t < 3) asm volatile("s_waitcnt vmcnt(8)" ::: "memory");
        else       asm volatile("s_waitcnt vmcnt(0)" ::: "memory");
        __builtin_amdgcn_sched_barrier(0);
        __builtin_amdgcn_s_barrier();
        __builtin_amdgcn_sched_barrier(0);
        const int buf = t & 1;
        __builtin_amdgcn_s_setprio(1);
#pragma unroll
        for (int kk = 0; kk < 2; ++kk){
            bf16x8 af[8], bf[4];
#pragma unroll
            for (int fm = 0; fm < 8; ++fm){
                int r = wm * 128 + fm * 16 + (lane & 15);
                int c = kk * 4 + (lane >> 4);
                af[fm] = *(const bf16x8*)&ldsA[buf][(r * 8 + (c ^ (r & 7))) * 8];
            }
#pragma unroll
            for (int fn = 0; fn < 4; ++fn){
                int r = wn * 64 + fn * 16 + (lane & 15);
                int c = kk * 4 + (lane >> 4);
                bf[fn] = *(const bf16x8*)&ldsB[buf][(r * 8 + (c ^ (r & 7))) * 8];
            }
#pragma unroll
            for (int fm = 0; fm < 8; ++fm)
#pragma unroll
                for (int fn = 0; fn < 4; ++fn)
                    acc[fm][fn] = __builtin_amdgcn_mfma_f32_16x16x32_bf16(
                        af[fm], bf[fn], acc[fm][fn], 0, 0, 0);
        }
        __builtin_amdgcn_s_setprio(0);
        __builtin_amdgcn_sched_barrier(0);
        __builtin_amdgcn_s_barrier();
        __builtin_amdgcn_sched_barrier(0);
        if (t < 2) stage(t & 1, (t + 2) * 64);
    }

#pragma unroll
    for (int fm = 0; fm < 8; ++fm){
#pragma unroll
        for (int fn = 0; fn < 4; ++fn){
            int xr = x0 + wm * 128 + fm * 16 + ((lane >> 4) << 2);
            int yc = y0 + wn * 64 + fn * 16 + (lane & 15);
            float bv = biasb[yc];
#pragma unroll
            for (int r = 0; r < 4; ++r)
                zb[(size_t)(xr + r) * QKVS + yc] = f2b(acc[fm][fn][r] + bv);
        }
    }
}

// --------- 3x3 window attention: 16 lanes per pixel, 4 pixels per wave ------
// out-of-bounds neighbors read the pad row (k=bk, v=bv) at qkv[NPIX]
__global__ __launch_bounds__(256)
void attn_win(const ushort* __restrict__ qkv, ushort* __restrict__ ctx){
    const int tid = threadIdx.x;
    const int lane = tid & 63, wid = tid >> 6;
    const int l16 = lane & 15, pg = lane >> 4;
    const int pix = blockIdx.x * 16 + wid * 4 + pg;
    const int b = pix >> 12, hw = pix & 4095;
    const int h = hw >> 6, w = hw & 63;
    const uint PADOFF = (uint)NPIX * QKVS;
    const int cbase = l16 * 16;

    // q: 16 channels per lane
    const ushort* qp = qkv + (size_t)pix * QKVS + cbase;
    uint4 qa = *(const uint4*)qp;
    uint4 qb = *(const uint4*)(qp + 8);
    float qf[16];
    unpack2(qa.x, qf[0], qf[1]);  unpack2(qa.y, qf[2], qf[3]);
    unpack2(qa.z, qf[4], qf[5]);  unpack2(qa.w, qf[6], qf[7]);
    unpack2(qb.x, qf[8], qf[9]);  unpack2(qb.y, qf[10], qf[11]);
    unpack2(qb.z, qf[12], qf[13]); unpack2(qb.w, qf[14], qf[15]);

    float lg[9];
    uint roff[9];
#pragma unroll
    for (int n = 0; n < 9; ++n){
        int nh = h + n / 3 - 1, nw = w + n % 3 - 1;
        bool ok = ((unsigned)nh < 64u) & ((unsigned)nw < 64u);
        roff[n] = ok ? (uint)(((b << 12) + (nh << 6) + nw) * QKVS) : PADOFF;
        const ushort* kp = qkv + roff[n] + 256 + cbase;
        uint4 ka = *(const uint4*)kp;
        uint4 kb = *(const uint4*)(kp + 8);
        float kf[16];
        unpack2(ka.x, kf[0], kf[1]);  unpack2(ka.y, kf[2], kf[3]);
        unpack2(ka.z, kf[4], kf[5]);  unpack2(ka.w, kf[6], kf[7]);
        unpack2(kb.x, kf[8], kf[9]);  unpack2(kb.y, kf[10], kf[11]);
        unpack2(kb.z, kf[12], kf[13]); unpack2(kb.w, kf[14], kf[15]);
        float d = 0.f;
#pragma unroll
        for (int j = 0; j < 16; ++j) d += qf[j] * kf[j];
        d += __shfl_xor(d, 1); d += __shfl_xor(d, 2);
        d += __shfl_xor(d, 4); d += __shfl_xor(d, 8);
        lg[n] = d;
    }
    float m = lg[0];
#pragma unroll
    for (int n = 1; n < 9; ++n) m = fmaxf(m, lg[n]);
    float e[9], s = 0.f;
#pragma unroll
    for (int n = 0; n < 9; ++n){ e[n] = __expf(lg[n] - m); s += e[n]; }
    float inv = 1.f / s;

    float c[16];
#pragma unroll
    for (int j = 0; j < 16; ++j) c[j] = 0.f;
#pragma unroll
    for (int n = 0; n < 9; ++n){
        float a = e[n] * inv;
        const ushort* vp = qkv + roff[n] + 512 + cbase;
        uint4 va = *(const uint4*)vp;
        uint4 vb = *(const uint4*)(vp + 8);
        float vf[16];
        unpack2(va.x, vf[0], vf[1]);  unpack2(va.y, vf[2], vf[3]);
        unpack2(va.z, vf[4], vf[5]);  unpack2(va.w, vf[6], vf[7]);
        unpack2(vb.x, vf[8], vf[9]);  unpack2(vb.y, vf[10], vf[11]);
        unpack2(vb.z, vf[12], vf[13]); unpack2(vb.w, vf[14], vf[15]);
#pragma unroll
        for (int j = 0; j < 16; ++j) c[j] += a * vf[j];
    }
    uint4 oa, ob;
    oa.x = cvtpk(c[0], c[1]);   oa.y = cvtpk(c[2], c[3]);
    oa.z = cvtpk(c[4], c[5]);   oa.w = cvtpk(c[6], c[7]);
    ob.x = cvtpk(c[8], c[9]);   ob.y = cvtpk(c[10], c[11]);
    ob.z = cvtpk(c[12], c[13]); ob.w = cvtpk(c[14], c[15]);
    ushort* op = ctx + (size_t)pix * 256 + cbase;
    *(uint4*)op = oa;
    *(uint4*)(op + 8) = ob;
}

// ------------- out GEMM (128x128, NCHW fp32 epilogue) -----------------------
__global__ __launch_bounds__(256, 2)
void gemm_out(const ushort* __restrict__ X, const ushort* __restrict__ Y,
              const float* __restrict__ bias, float* __restrict__ zf){
    __shared__ ushort ldsX[2][128 * 64];
    __shared__ ushort ldsY[2][128 * 64];
    const int tid  = threadIdx.x;
    const int lane = tid & 63;
    const int wid  = tid >> 6;
    const int wm   = wid >> 1, wn = wid & 1;
    const int x0   = blockIdx.x * 128, y0 = blockIdx.y * 128;

    auto stage = [&](int buf, int k0){
#pragma unroll
        for (int i = 0; i < 4; ++i){
            int f   = i * 256 + tid;
            int row = f >> 3, cp = f & 7;
            int cs  = cp ^ (row & 7);
            const ushort* gx = X + (size_t)(x0 + row) * KDIM + k0 + cs * 8;
            const ushort* gy = Y + (size_t)(y0 + row) * KDIM + k0 + cs * 8;
            __builtin_amdgcn_global_load_lds(
                (const __attribute__((address_space(1))) void*)gx,
                (__attribute__((address_space(3))) void*)&ldsX[buf][f * 8], 16, 0, 0);
            __builtin_amdgcn_global_load_lds(
                (const __attribute__((address_space(1))) void*)gy,
                (__attribute__((address_space(3))) void*)&ldsY[buf][f * 8], 16, 0, 0);
        }
    };

    f32x4 acc[4][4];
#pragma unroll
    for (int i = 0; i < 4; ++i)
#pragma unroll
        for (int j = 0; j < 4; ++j) acc[i][j] = f32x4{0.f, 0.f, 0.f, 0.f};

    stage(0, 0);
    int buf = 0;
    for (int t = 0; t < 4; ++t){
        __syncthreads();
        if (t < 3) stage(buf ^ 1, (t + 1) * 64);
#pragma unroll
        for (int kk = 0; kk < 2; ++kk){
            bf16x8 xa[4], yb[4];
#pragma unroll
            for (int fm = 0; fm < 4; ++fm){
                int r = wm * 64 + fm * 16 + (lane & 15);
                int c = kk * 4 + (lane >> 4);
                xa[fm] = *(const bf16x8*)&ldsX[buf][(r * 8 + (c ^ (r & 7))) * 8];
            }
#pragma unroll
            for (int fn = 0; fn < 4; ++fn){
                int r = wn * 64 + fn * 16 + (lane & 15);
                int c = kk * 4 + (lane >> 4);
                yb[fn] = *(const bf16x8*)&ldsY[buf][(r * 8 + (c ^ (r & 7))) * 8];
            }
#pragma unroll
            for (int fm = 0; fm < 4; ++fm)
#pragma unroll
                for (int fn = 0; fn < 4; ++fn)
                    acc[fm][fn] = __builtin_amdgcn_mfma_f32_16x16x32_bf16(
                        xa[fm], yb[fn], acc[fm][fn], 0, 0, 0);
        }
        buf ^= 1;
    }

#pragma unroll
    for (int fm = 0; fm < 4; ++fm){
#pragma unroll
        for (int fn = 0; fn < 4; ++fn){
            int xr = x0 + wm * 64 + fm * 16 + ((lane >> 4) << 2);
            int yc = y0 + wn * 64 + fn * 16 + (lane & 15);
            int bpix = yc >> 12, hw = yc & 4095;
#pragma unroll
            for (int r = 0; r < 4; ++r){
                int ch = xr + r;
                zf[((size_t)(bpix * 256 + ch)) * 4096 + hw] =
                    acc[fm][fn][r] + bias[ch];
            }
        }
    }
}

// ---------------------------------------------------------------------------
extern "C" void kernel_launch(void* const* d_in, const int* in_sizes, int n_in,
                              void* d_out, int out_size, void* d_ws, size_t ws_size,
                              hipStream_t stream){
    const float* x  = (const float*)d_in[0];
    const float* Wq = (const float*)d_in[1];
    const float* bq = (const float*)d_in[2];
    const float* Wk = (const float*)d_in[3];
    const float* bk = (const float*)d_in[4];
    const float* Wv = (const float*)d_in[5];
    const float* bv = (const float*)d_in[6];
    const float* Wo = (const float*)d_in[7];
    const float* bo = (const float*)d_in[8];
    float* out = (float*)d_out;

    char* ws = (char*)d_ws;
    ushort* wtq    = (ushort*)(ws);                // [4][768][256] bf16
    ushort* wot    = (ushort*)(ws + 1572864);      // [256][256] bf16
    float*  biasp  = (float*) (ws + 1703936);      // [4][768]
    float*  psum   = (float*) (ws + 1716224);      // [256][256]
    float*  psum2  = (float*) (ws + 1978368);      // [256][256]
    ushort* xt     = (ushort*)(ws + 2240512);      // [NPIX][256] bf16
    ushort* qkv    = (ushort*)(ws + 10629120);     // [NPIX+1][768] bf16 (+pad row)
    ushort* ctx    = (ushort*)(ws + 35796480);     // [NPIX][256] bf16

    ln_fuse<<<512, 256, 0, stream>>>(x, xt, psum, psum2);
    prep2<<<269, 256, 0, stream>>>(Wq, bq, Wk, bk, Wv, bv, Wo,
                                   psum, psum2, wtq, wot, biasp, qkv);

    gemm_qkv<<<192, 512, 0, stream>>>(xt, wtq, biasp, qkv);   // 64 M x 3 N tiles

    attn_win<<<1024, 256, 0, stream>>>(qkv, ctx);

    dim3 g2(2, 128);
    gemm_out<<<g2, 256, 0, stream>>>(wot, ctx, bo, out);
}